// Round 2
// baseline (919.862 us; speedup 1.0000x reference)
//
#include <hip/hip_runtime.h>
#include <stdint.h>

// Problem constants
// B=2, L=2048, D=512, H=8, DK=DV=64, TEMP=8, LN_EPS=1e-5

typedef float fx4 __attribute__((ext_vector_type(4)));
typedef short bfx8 __attribute__((ext_vector_type(8)));
typedef short sx4 __attribute__((ext_vector_type(4)));

#define MFMA16(a, b, c) __builtin_amdgcn_mfma_f32_16x16x32_bf16((a), (b), (c), 0, 0, 0)

__device__ __forceinline__ unsigned short f2bf(float f) {
  union { float f; uint32_t u; } v; v.f = f;
  uint32_t r = v.u + 0x7FFFu + ((v.u >> 16) & 1u);  // RNE
  return (unsigned short)(r >> 16);
}

__device__ __forceinline__ bfx8 ldbf8(const unsigned short* p) {
  return *reinterpret_cast<const bfx8*>(p);
}

__device__ __forceinline__ bfx8 cvt8(const float* p) {
  fx4 a = *reinterpret_cast<const fx4*>(p);
  fx4 b = *reinterpret_cast<const fx4*>(p + 4);
  bfx8 r;
  r[0] = (short)f2bf(a[0]); r[1] = (short)f2bf(a[1]);
  r[2] = (short)f2bf(a[2]); r[3] = (short)f2bf(a[3]);
  r[4] = (short)f2bf(b[0]); r[5] = (short)f2bf(b[1]);
  r[6] = (short)f2bf(b[2]); r[7] = (short)f2bf(b[3]);
  return r;
}

// ---------------- kernel 0: weight bf16 convert + mask bitpack (fused) ----------
__global__ __launch_bounds__(256) void k_prep(const float* __restrict__ s0,
                                              const float* __restrict__ s1,
                                              const float* __restrict__ s2,
                                              const float* __restrict__ s3,
                                              unsigned short* __restrict__ dst,
                                              const int* __restrict__ mask,
                                              unsigned long long* __restrict__ mbits) {
  int bid = blockIdx.x;
  if (bid < 1024) {
    int y = bid >> 8;
    const float* s = (y == 0) ? s0 : (y == 1) ? s1 : (y == 2) ? s2 : s3;
    int i = ((bid & 255) * 256 + threadIdx.x) * 4;
    fx4 v = *reinterpret_cast<const fx4*>(s + i);
    sx4 o;
    o[0] = (short)f2bf(v[0]); o[1] = (short)f2bf(v[1]);
    o[2] = (short)f2bf(v[2]); o[3] = (short)f2bf(v[3]);
    *reinterpret_cast<sx4*>(dst + y * 262144 + i) = o;
  } else {
    int i = (bid - 1024) * 256 + threadIdx.x;  // total 8388608
    unsigned long long b = __ballot(mask[i] != 0);
    if ((threadIdx.x & 63) == 0) mbits[i >> 6] = b;
  }
}

// ---------------- kernel 1: projection GEMMs, all 3 in one launch (blockIdx.z) --
// z=0: Qb [B,H,L,64] ; z=1: Kb same ; z=2: Vt [B,H,64,L] (transposed)
__global__ __launch_bounds__(256) void k_proj(const float* __restrict__ Xq,
                                              const float* __restrict__ Xk,
                                              const float* __restrict__ Xv,
                                              const unsigned short* __restrict__ Wb,
                                              const float* __restrict__ bq,
                                              const float* __restrict__ bk,
                                              const float* __restrict__ bv,
                                              unsigned short* __restrict__ Qb,
                                              unsigned short* __restrict__ Kb,
                                              unsigned short* __restrict__ Vt) {
  int z = blockIdx.z;
  const float* X = (z == 0) ? Xq : (z == 1) ? Xk : Xv;
  const unsigned short* W = Wb + (size_t)z * 262144;
  const float* bias = (z == 0) ? bq : (z == 1) ? bk : bv;
  unsigned short* dst = (z == 0) ? Qb : (z == 1) ? Kb : Vt;

  int wave = threadIdx.x >> 6, lane = threadIdx.x & 63;
  int quad = lane >> 4, tn = lane & 15;
  int m0 = blockIdx.x * 64 + wave * 16;   // 64 blocks.x -> 4096 rows
  int n0 = blockIdx.y * 64;               // 8 blocks.y  -> 512 cols
  fx4 acc[4];
  #pragma unroll
  for (int i = 0; i < 4; ++i) acc[i] = (fx4){0.f, 0.f, 0.f, 0.f};

  const float* xrow = X + (size_t)(m0 + tn) * 512;
  for (int k0 = 0; k0 < 512; k0 += 32) {
    bfx8 af = cvt8(xrow + k0 + quad * 8);
    #pragma unroll
    for (int nt = 0; nt < 4; ++nt) {
      const unsigned short* wp = W + (size_t)(n0 + nt * 16 + tn) * 512 + k0 + quad * 8;
      acc[nt] = MFMA16(af, ldbf8(wp), acc[nt]);
    }
  }

  #pragma unroll
  for (int nt = 0; nt < 4; ++nt) {
    int n = n0 + nt * 16 + tn;
    int h = n >> 6, dd = n & 63;
    float bvv = bias[n];
    if (z == 2) {
      int r0 = m0 + quad * 4;          // 4 consecutive rows, same batch
      int b = r0 >> 11, l = r0 & 2047;
      sx4 o;
      #pragma unroll
      for (int i = 0; i < 4; ++i) o[i] = (short)f2bf(acc[nt][i] + bvv);
      unsigned short* vp = dst + (size_t)((b * 8 + h) * 64 + dd) * 2048 + l;
      *reinterpret_cast<sx4*>(vp) = o;
    } else {
      #pragma unroll
      for (int i = 0; i < 4; ++i) {
        int r = m0 + quad * 4 + i;
        int b = r >> 11, l = r & 2047;
        dst[(size_t)((b * 8 + h) * 2048 + l) * 64 + dd] = f2bf(acc[nt][i] + bvv);
      }
    }
  }
}

// ---------------- kernel 2a: scores + online softmax stats ---------------------
// Per block: (b,h) x 16 q-rows, stream all 128 key-tiles. Raw masked/gated scores
// written f32 to the attn buffer; per-row (max, 1/sum) to stats. LDS = 512 B.
__global__ __launch_bounds__(256) void k_score(const unsigned short* __restrict__ Qb,
                                               const unsigned short* __restrict__ Kb,
                                               const float* __restrict__ gate,
                                               const unsigned long long* __restrict__ mbits,
                                               float* __restrict__ Sraw,
                                               float2* __restrict__ stats) {
  __shared__ float sm_m[4][16];
  __shared__ float sm_s[4][16];

  int wave = threadIdx.x >> 6, lane = threadIdx.x & 63;
  int quad = lane >> 4, tn = lane & 15;

  int lin = blockIdx.x;            // 0..2047
  int xcd = lin & 7;
  int ix  = lin >> 3;              // 0..255
  int bh  = xcd * 2 + (ix >> 7);   // each XCD owns 2 (b,h) pairs -> K L2-resident
  int qt  = ix & 127;
  int b = bh >> 3;
  int q0 = qt * 16;

  const unsigned short* Qbase = Qb + ((size_t)bh * 2048 + q0) * 64;
  bfx8 aq0 = ldbf8(Qbase + tn * 64 + quad * 8);
  bfx8 aq1 = ldbf8(Qbase + tn * 64 + 32 + quad * 8);
  const unsigned short* Kbase = Kb + (size_t)bh * 2048 * 64;
  const float* gbase = gate + ((size_t)bh * 2048 + q0 + quad * 4) * 2048 + tn;
  float* srow_base = Sraw + ((size_t)bh * 2048 + q0 + quad * 4) * 2048 + tn;
  const unsigned long long* mbase = mbits + (size_t)(b * 2048 + q0 + quad * 4) * 32;

  float m[4], s[4];
  #pragma unroll
  for (int i = 0; i < 4; ++i) { m[i] = -3.0e38f; s[i] = 0.f; }

  #pragma unroll 4
  for (int kt = wave; kt < 128; kt += 4) {
    int key0 = kt * 16;
    const unsigned short* kp = Kbase + (size_t)(key0 + tn) * 64 + quad * 8;
    bfx8 kb0 = ldbf8(kp);
    bfx8 kb1 = ldbf8(kp + 32);
    fx4 d = (fx4){0.f, 0.f, 0.f, 0.f};
    d = MFMA16(aq0, kb0, d);
    d = MFMA16(aq1, kb1, d);
    const float* gp = gbase + key0;
    int wi = kt >> 2;               // (key0+tn)>>6, tn<16
    int bit = (key0 & 63) + tn;     // (key0+tn)&63
    #pragma unroll
    for (int i = 0; i < 4; ++i) {
      float g = gp[(size_t)i * 2048];
      unsigned long long mw = mbase[i * 32 + wi];
      float v = d[i] * 0.125f * g;
      bool msk = (mw >> bit) & 1ull;
      if (msk) v = -3.0e38f;
      srow_base[(size_t)i * 2048 + key0] = v;
      float nm = fmaxf(m[i], v);
      s[i] = s[i] * __expf(m[i] - nm) + (msk ? 0.f : __expf(v - nm));
      m[i] = nm;
    }
  }

  // reduce (m,s) across the 16 tn lanes (columns of this wave's key subset)
  #pragma unroll
  for (int off = 1; off < 16; off <<= 1) {
    #pragma unroll
    for (int i = 0; i < 4; ++i) {
      float om = __shfl_xor(m[i], off);
      float os = __shfl_xor(s[i], off);
      float nm = fmaxf(m[i], om);
      s[i] = s[i] * __expf(m[i] - nm) + os * __expf(om - nm);
      m[i] = nm;
    }
  }
  if (tn == 0) {
    #pragma unroll
    for (int i = 0; i < 4; ++i) {
      sm_m[wave][quad * 4 + i] = m[i];
      sm_s[wave][quad * 4 + i] = s[i];
    }
  }
  __syncthreads();
  if (threadIdx.x < 16) {
    float fm = sm_m[0][threadIdx.x], fs = sm_s[0][threadIdx.x];
    #pragma unroll
    for (int w = 1; w < 4; ++w) {
      float om = sm_m[w][threadIdx.x], os = sm_s[w][threadIdx.x];
      float nm = fmaxf(fm, om);
      fs = fs * __expf(fm - nm) + os * __expf(om - nm);
      fm = nm;
    }
    stats[(size_t)bh * 2048 + q0 + threadIdx.x] = make_float2(fm, 1.0f / fs);
  }
}

// ---------------- kernel 2b: normalize attn in place + PV ----------------------
// Per block: (b,h) x 8 q-rows. Phase 1: read raw S, p=exp(s-m)*inv, rewrite attn,
// stash bf16 P in 32KB XOR-swizzled LDS. Phase 2: O = P @ V^T via MFMA.
__global__ __launch_bounds__(256) void k_pv(float* __restrict__ SA,
                                            const unsigned short* __restrict__ Vt,
                                            const float2* __restrict__ stats,
                                            unsigned short* __restrict__ Ob) {
  __shared__ unsigned short P[8 * 2048];   // 32 KB, 16B-block XOR swizzle by row

  int wave = threadIdx.x >> 6, lane = threadIdx.x & 63;
  int quad = lane >> 4, tn = lane & 15;

  int lin = blockIdx.x;            // 0..4095
  int xcd = lin & 7;
  int ix  = lin >> 3;              // 0..511
  int bh  = xcd * 2 + (ix >> 8);
  int qt  = ix & 255;
  int b = bh >> 3, h = bh & 7;
  int q0 = qt * 8;

  // ---- phase 1: wave handles rows 2w, 2w+1 -----------------------------------
  #pragma unroll
  for (int rr = 0; rr < 2; ++rr) {
    int r = wave * 2 + rr;
    float* srow = SA + ((size_t)bh * 2048 + q0 + r) * 2048;
    float2 st = stats[(size_t)bh * 2048 + q0 + r];
    float mr = st.x, inv = st.y;
    #pragma unroll
    for (int it = 0; it < 8; ++it) {
      int k4 = lane + it * 64;               // fx4 index 0..511
      fx4 sv = *reinterpret_cast<fx4*>(srow + k4 * 4);
      fx4 p;
      #pragma unroll
      for (int i = 0; i < 4; ++i) p[i] = __expf(sv[i] - mr) * inv;
      *reinterpret_cast<fx4*>(srow + k4 * 4) = p;   // normalized attn, in place
      sx4 pk;
      #pragma unroll
      for (int i = 0; i < 4; ++i) pk[i] = (short)f2bf(p[i]);
      int addr = r * 2048 + ((((k4 >> 1) ^ r) << 3) | ((k4 & 1) * 4));
      *reinterpret_cast<sx4*>(&P[addr]) = pk;
    }
  }
  __syncthreads();

  // ---- phase 2: wave w -> dv [16w, 16w+16), M=8 valid rows -------------------
  fx4 acc = (fx4){0.f, 0.f, 0.f, 0.f};
  int pr = tn & 7;                            // A rows 8..15 duplicate 0..7
  const unsigned short* vbase = Vt + ((size_t)bh * 64 + wave * 16 + tn) * 2048;
  #pragma unroll 4
  for (int kt = 0; kt < 64; ++kt) {
    int b8 = kt * 4 + quad;
    bfx8 af = *reinterpret_cast<bfx8*>(&P[pr * 2048 + ((b8 ^ pr) << 3)]);
    bfx8 bv = ldbf8(vbase + kt * 32 + quad * 8);
    acc = MFMA16(af, bv, acc);
  }
  if (quad < 2) {
    #pragma unroll
    for (int i = 0; i < 4; ++i) {
      int rq = quad * 4 + i;                  // valid D rows 0..7
      Ob[(size_t)(b * 2048 + q0 + rq) * 512 + h * 64 + wave * 16 + tn] = f2bf(acc[i]);
    }
  }
}

// ---------------- kernel 3: FC + bias + residual + LayerNorm --------------------
#define XPITCH 516
__global__ __launch_bounds__(256) void k_fc_ln(const unsigned short* __restrict__ Ob,
                                               const unsigned short* __restrict__ Wfcb,
                                               const float* __restrict__ bfc,
                                               const float* __restrict__ resid,
                                               const float* __restrict__ lng,
                                               const float* __restrict__ lnb,
                                               float* __restrict__ out) {
  __shared__ float xb[16 * XPITCH];
  int wave = threadIdx.x >> 6, lane = threadIdx.x & 63;
  int quad = lane >> 4, tn = lane & 15;
  int m0 = blockIdx.x * 16;   // 256 blocks -> 4096 rows

  fx4 acc[8];
  #pragma unroll
  for (int i = 0; i < 8; ++i) acc[i] = (fx4){0.f, 0.f, 0.f, 0.f};

  const unsigned short* arow = Ob + (size_t)(m0 + tn) * 512;
  for (int k0 = 0; k0 < 512; k0 += 32) {
    bfx8 af = ldbf8(arow + k0 + quad * 8);
    #pragma unroll
    for (int nt = 0; nt < 8; ++nt) {
      const unsigned short* wp = Wfcb + (size_t)(wave * 128 + nt * 16 + tn) * 512 + k0 + quad * 8;
      acc[nt] = MFMA16(af, ldbf8(wp), acc[nt]);
    }
  }
  #pragma unroll
  for (int nt = 0; nt < 8; ++nt) {
    int col = wave * 128 + nt * 16 + tn;
    #pragma unroll
    for (int i = 0; i < 4; ++i) xb[(quad * 4 + i) * XPITCH + col] = acc[nt][i];
  }
  __syncthreads();

  #pragma unroll
  for (int ri = 0; ri < 4; ++ri) {
    int r = wave * 4 + ri;
    int row = m0 + r;
    float* xr = xb + r * XPITCH;
    const float* qr = resid + (size_t)row * 512;
    float sum = 0.f, sq = 0.f;
    #pragma unroll
    for (int it = 0; it < 2; ++it) {
      int i4 = lane + it * 64;  // 0..127
      fx4 x = *reinterpret_cast<fx4*>(xr + i4 * 4);
      fx4 bb = *reinterpret_cast<const fx4*>(bfc + i4 * 4);
      fx4 rr = *reinterpret_cast<const fx4*>(qr + i4 * 4);
      x = x + bb + rr;
      *reinterpret_cast<fx4*>(xr + i4 * 4) = x;
      sum += x[0] + x[1] + x[2] + x[3];
      sq  += x[0]*x[0] + x[1]*x[1] + x[2]*x[2] + x[3]*x[3];
    }
    #pragma unroll
    for (int off = 32; off; off >>= 1) {
      sum += __shfl_xor(sum, off);
      sq  += __shfl_xor(sq, off);
    }
    float mu = sum * (1.f / 512.f);
    float var = sq * (1.f / 512.f) - mu * mu;
    float rstd = rsqrtf(var + 1e-5f);
    #pragma unroll
    for (int it = 0; it < 2; ++it) {
      int i4 = lane + it * 64;
      fx4 x = *reinterpret_cast<fx4*>(xr + i4 * 4);
      fx4 gg = *reinterpret_cast<const fx4*>(lng + i4 * 4);
      fx4 be = *reinterpret_cast<const fx4*>(lnb + i4 * 4);
      fx4 y = (x - mu) * rstd * gg + be;
      *reinterpret_cast<fx4*>(out + (size_t)row * 512 + i4 * 4) = y;
    }
  }
}

// ---------------- launcher ------------------------------------------------------
extern "C" void kernel_launch(void* const* d_in, const int* in_sizes, int n_in,
                              void* d_out, int out_size, void* d_ws, size_t ws_size,
                              hipStream_t stream) {
  const float* q    = (const float*)d_in[0];
  const float* k    = (const float*)d_in[1];
  const float* v    = (const float*)d_in[2];
  const int*   mask = (const int*)d_in[3];
  const float* gate = (const float*)d_in[4];
  const float* w_qs = (const float*)d_in[5];
  const float* b_qs = (const float*)d_in[6];
  const float* w_ks = (const float*)d_in[7];
  const float* b_ks = (const float*)d_in[8];
  const float* w_vs = (const float*)d_in[9];
  const float* b_vs = (const float*)d_in[10];
  const float* w_fc = (const float*)d_in[11];
  const float* b_fc = (const float*)d_in[12];
  const float* ln_g = (const float*)d_in[13];
  const float* ln_b = (const float*)d_in[14];
  float* out = (float*)d_out;

  char* ws = (char*)d_ws;
  unsigned short* Qb = (unsigned short*)(ws);                    //  4 MB
  unsigned short* Kb = (unsigned short*)(ws + 4194304);          //  4 MB
  unsigned short* Vt = (unsigned short*)(ws + 8388608);          //  4 MB
  unsigned short* Ob = (unsigned short*)(ws + 12582912);         //  4 MB
  unsigned short* Wb = (unsigned short*)(ws + 16777216);         //  2 MB (4 x 512KB)
  unsigned long long* mbits = (unsigned long long*)(ws + 18874368);  // 1 MB
  float2* stats = (float2*)(ws + 19922944);                      // 256 KB

  float* attn = out + 2097152;   // [B,H,L,L] f32 output region (raw S then normalized)

  k_prep<<<33792, 256, 0, stream>>>(w_qs, w_ks, w_vs, w_fc, Wb, mask, mbits);
  k_proj<<<dim3(64, 8, 3), 256, 0, stream>>>(q, k, v, Wb, b_qs, b_ks, b_vs, Qb, Kb, Vt);
  k_score<<<2048, 256, 0, stream>>>(Qb, Kb, gate, mbits, attn, stats);
  k_pv<<<4096, 256, 0, stream>>>(attn, Vt, stats, Ob);
  k_fc_ln<<<256, 256, 0, stream>>>(Ob, Wb + 786432, b_fc, q, ln_g, ln_b, out);
}

// Round 3
// 814.121 us; speedup vs baseline: 1.1299x; 1.1299x over previous
//
#include <hip/hip_runtime.h>
#include <stdint.h>

// Problem constants
// B=2, L=2048, D=512, H=8, DK=DV=64, TEMP=8, LN_EPS=1e-5

typedef float fx4 __attribute__((ext_vector_type(4)));
typedef short bfx8 __attribute__((ext_vector_type(8)));
typedef short sx4 __attribute__((ext_vector_type(4)));

#define MFMA16(a, b, c) __builtin_amdgcn_mfma_f32_16x16x32_bf16((a), (b), (c), 0, 0, 0)

__device__ __forceinline__ unsigned short f2bf(float f) {
  union { float f; uint32_t u; } v; v.f = f;
  uint32_t r = v.u + 0x7FFFu + ((v.u >> 16) & 1u);  // RNE
  return (unsigned short)(r >> 16);
}

__device__ __forceinline__ bfx8 ldbf8(const unsigned short* p) {
  return *reinterpret_cast<const bfx8*>(p);
}

__device__ __forceinline__ bfx8 cvt8(const float* p) {
  fx4 a = *reinterpret_cast<const fx4*>(p);
  fx4 b = *reinterpret_cast<const fx4*>(p + 4);
  bfx8 r;
  r[0] = (short)f2bf(a[0]); r[1] = (short)f2bf(a[1]);
  r[2] = (short)f2bf(a[2]); r[3] = (short)f2bf(a[3]);
  r[4] = (short)f2bf(b[0]); r[5] = (short)f2bf(b[1]);
  r[6] = (short)f2bf(b[2]); r[7] = (short)f2bf(b[3]);
  return r;
}

// ---------------- kernel 0: weight bf16 convert + mask bitpack (fused) ----------
__global__ __launch_bounds__(256) void k_prep(const float* __restrict__ s0,
                                              const float* __restrict__ s1,
                                              const float* __restrict__ s2,
                                              const float* __restrict__ s3,
                                              unsigned short* __restrict__ dst,
                                              const int* __restrict__ mask,
                                              unsigned long long* __restrict__ mbits) {
  int bid = blockIdx.x;
  if (bid < 1024) {
    int y = bid >> 8;
    const float* s = (y == 0) ? s0 : (y == 1) ? s1 : (y == 2) ? s2 : s3;
    int i = ((bid & 255) * 256 + threadIdx.x) * 4;
    fx4 v = *reinterpret_cast<const fx4*>(s + i);
    sx4 o;
    o[0] = (short)f2bf(v[0]); o[1] = (short)f2bf(v[1]);
    o[2] = (short)f2bf(v[2]); o[3] = (short)f2bf(v[3]);
    *reinterpret_cast<sx4*>(dst + y * 262144 + i) = o;
  } else {
    int i = (bid - 1024) * 256 + threadIdx.x;  // total 8388608
    unsigned long long b = __ballot(mask[i] != 0);
    if ((threadIdx.x & 63) == 0) mbits[i >> 6] = b;
  }
}

// ---------------- kernel 1: projection GEMMs, all 3 in one launch (blockIdx.z) --
// z=0: Qb [B,H,L,64] ; z=1: Kb same ; z=2: Vt [B,H,64,L] (transposed)
__global__ __launch_bounds__(256) void k_proj(const float* __restrict__ Xq,
                                              const float* __restrict__ Xk,
                                              const float* __restrict__ Xv,
                                              const unsigned short* __restrict__ Wb,
                                              const float* __restrict__ bq,
                                              const float* __restrict__ bk,
                                              const float* __restrict__ bv,
                                              unsigned short* __restrict__ Qb,
                                              unsigned short* __restrict__ Kb,
                                              unsigned short* __restrict__ Vt) {
  int z = blockIdx.z;
  const float* X = (z == 0) ? Xq : (z == 1) ? Xk : Xv;
  const unsigned short* W = Wb + (size_t)z * 262144;
  const float* bias = (z == 0) ? bq : (z == 1) ? bk : bv;
  unsigned short* dst = (z == 0) ? Qb : (z == 1) ? Kb : Vt;

  int wave = threadIdx.x >> 6, lane = threadIdx.x & 63;
  int quad = lane >> 4, tn = lane & 15;
  int m0 = blockIdx.x * 64 + wave * 16;   // 64 blocks.x -> 4096 rows
  int n0 = blockIdx.y * 64;               // 8 blocks.y  -> 512 cols
  fx4 acc[4];
  #pragma unroll
  for (int i = 0; i < 4; ++i) acc[i] = (fx4){0.f, 0.f, 0.f, 0.f};

  const float* xrow = X + (size_t)(m0 + tn) * 512;
  for (int k0 = 0; k0 < 512; k0 += 32) {
    bfx8 af = cvt8(xrow + k0 + quad * 8);
    #pragma unroll
    for (int nt = 0; nt < 4; ++nt) {
      const unsigned short* wp = W + (size_t)(n0 + nt * 16 + tn) * 512 + k0 + quad * 8;
      acc[nt] = MFMA16(af, ldbf8(wp), acc[nt]);
    }
  }

  #pragma unroll
  for (int nt = 0; nt < 4; ++nt) {
    int n = n0 + nt * 16 + tn;
    int h = n >> 6, dd = n & 63;
    float bvv = bias[n];
    if (z == 2) {
      int r0 = m0 + quad * 4;          // 4 consecutive rows, same batch
      int b = r0 >> 11, l = r0 & 2047;
      sx4 o;
      #pragma unroll
      for (int i = 0; i < 4; ++i) o[i] = (short)f2bf(acc[nt][i] + bvv);
      unsigned short* vp = dst + (size_t)((b * 8 + h) * 64 + dd) * 2048 + l;
      *reinterpret_cast<sx4*>(vp) = o;
    } else {
      #pragma unroll
      for (int i = 0; i < 4; ++i) {
        int r = m0 + quad * 4 + i;
        int b = r >> 11, l = r & 2047;
        dst[(size_t)((b * 8 + h) * 2048 + l) * 64 + dd] = f2bf(acc[nt][i] + bvv);
      }
    }
  }
}

// ---------------- kernel 2: single-pass attention, 8 q-rows/block ---------------
// 256 thr (4 waves), LDS 65.7KB -> 2 blocks/CU so phases of neighbor blocks overlap.
// Phase A: raw QK^T/8 -> LDS (MFMA, rows duplicated 2x in the 16-row tile)
// Phase B: per-row fx4-coalesced: gate*s, mask, max, exp, sum, write normalized
//          attn to global AND normalized P back to LDS (regs hold the row slice)
// Phase D: O = P @ V via MFMA from LDS; V L2-resident (XCD swizzle: 2 bh per XCD)
#define SPITCH 2052
__global__ __launch_bounds__(256) void k_attn(const unsigned short* __restrict__ Qb,
                                              const unsigned short* __restrict__ Kb,
                                              const unsigned short* __restrict__ Vt,
                                              const float* __restrict__ gate,
                                              const unsigned long long* __restrict__ mbits,
                                              float* __restrict__ attn_out,
                                              unsigned short* __restrict__ Ob) {
  __shared__ float S[8 * SPITCH];   // 65.7 KB score/P strip

  int wave = threadIdx.x >> 6, lane = threadIdx.x & 63;
  int quad = lane >> 4, tn = lane & 15;

  int lin = blockIdx.x;            // 0..4095
  int xcd = lin & 7;
  int ix  = lin >> 3;              // 0..511
  int bh  = xcd * 2 + (ix >> 8);   // each XCD owns 2 (b,h): K/V stay L2-resident
  int qt  = ix & 255;
  int b = bh >> 3, h = bh & 7;
  int q0 = qt * 8;

  // ---- phase A: raw scores (QK^T)/8 -> LDS, 4 waves stride key tiles ---------
  const unsigned short* Qbase = Qb + ((size_t)bh * 2048 + q0) * 64;
  bfx8 aq0 = ldbf8(Qbase + (size_t)(tn & 7) * 64 + quad * 8);
  bfx8 aq1 = ldbf8(Qbase + (size_t)(tn & 7) * 64 + 32 + quad * 8);
  const unsigned short* Kbase = Kb + (size_t)bh * 2048 * 64;
  #pragma unroll 4
  for (int kt = wave; kt < 128; kt += 4) {
    int key0 = kt * 16;
    const unsigned short* kp = Kbase + (size_t)(key0 + tn) * 64 + quad * 8;
    bfx8 b0 = ldbf8(kp);
    bfx8 b1 = ldbf8(kp + 32);
    fx4 d = (fx4){0.f, 0.f, 0.f, 0.f};
    d = MFMA16(aq0, b0, d);
    d = MFMA16(aq1, b1, d);
    if (quad < 2) {           // rows 8..15 duplicate rows 0..7 -> skip
      #pragma unroll
      for (int i = 0; i < 4; ++i)
        S[(quad * 4 + i) * SPITCH + key0 + tn] = d[i] * 0.125f;
    }
  }
  __syncthreads();

  // ---- phase B: wave w owns rows 2w, 2w+1; fully coalesced gate/attn streams --
  #pragma unroll
  for (int rr = 0; rr < 2; ++rr) {
    int r = wave * 2 + rr;
    float* srow = S + r * SPITCH;
    const float* grow = gate + ((size_t)bh * 2048 + q0 + r) * 2048;
    const unsigned long long* mrow = mbits + (size_t)(b * 2048 + q0 + r) * 32;
    fx4 sv[8];
    float lmax = -3.0e38f;
    #pragma unroll
    for (int it = 0; it < 8; ++it) {
      int k4 = lane + it * 64;     // fx4 index 0..511
      fx4 s = *reinterpret_cast<fx4*>(srow + k4 * 4);
      fx4 g = *reinterpret_cast<const fx4*>(grow + k4 * 4);
      unsigned long long mw = mrow[k4 >> 4];
      int sh = (k4 & 15) * 4;
      #pragma unroll
      for (int i = 0; i < 4; ++i) {
        float vv = s[i] * g[i];
        if ((mw >> (sh + i)) & 1ull) vv = -3.0e38f;
        s[i] = vv;
        lmax = fmaxf(lmax, vv);
      }
      sv[it] = s;
    }
    #pragma unroll
    for (int off = 32; off; off >>= 1) lmax = fmaxf(lmax, __shfl_xor(lmax, off));
    float lsum = 0.f;
    #pragma unroll
    for (int it = 0; it < 8; ++it) {
      fx4 s = sv[it];
      #pragma unroll
      for (int i = 0; i < 4; ++i) {
        float p = __expf(s[i] - lmax);
        s[i] = p;
        lsum += p;
      }
      sv[it] = s;
    }
    #pragma unroll
    for (int off = 32; off; off >>= 1) lsum += __shfl_xor(lsum, off);
    float inv = 1.0f / lsum;
    float* orow = attn_out + ((size_t)bh * 2048 + q0 + r) * 2048;
    #pragma unroll
    for (int it = 0; it < 8; ++it) {
      int k4 = lane + it * 64;
      fx4 p = sv[it] * inv;
      *reinterpret_cast<fx4*>(orow + k4 * 4) = p;   // normalized attn (coalesced)
      *reinterpret_cast<fx4*>(srow + k4 * 4) = p;   // normalized P for PV
    }
  }
  __syncthreads();

  // ---- phase D: O = P @ V, wave w covers dv [16w,16w+16), 8 valid rows -------
  fx4 acc = (fx4){0.f, 0.f, 0.f, 0.f};
  const unsigned short* vbase = Vt + ((size_t)bh * 64 + wave * 16 + tn) * 2048;
  const float* prow = S + (tn & 7) * SPITCH;
  #pragma unroll 4
  for (int kt = 0; kt < 64; ++kt) {
    bfx8 af = cvt8(prow + kt * 32 + quad * 8);
    bfx8 bv = ldbf8(vbase + kt * 32 + quad * 8);
    acc = MFMA16(af, bv, acc);
  }
  if (quad < 2) {
    #pragma unroll
    for (int i = 0; i < 4; ++i) {
      int qg = q0 + quad * 4 + i;
      Ob[(size_t)(b * 2048 + qg) * 512 + h * 64 + wave * 16 + tn] = f2bf(acc[i]);
    }
  }
}

// ---------------- kernel 3: FC + bias + residual + LayerNorm --------------------
#define XPITCH 516
__global__ __launch_bounds__(256) void k_fc_ln(const unsigned short* __restrict__ Ob,
                                               const unsigned short* __restrict__ Wfcb,
                                               const float* __restrict__ bfc,
                                               const float* __restrict__ resid,
                                               const float* __restrict__ lng,
                                               const float* __restrict__ lnb,
                                               float* __restrict__ out) {
  __shared__ float xb[16 * XPITCH];
  int wave = threadIdx.x >> 6, lane = threadIdx.x & 63;
  int quad = lane >> 4, tn = lane & 15;
  int m0 = blockIdx.x * 16;   // 256 blocks -> 4096 rows

  fx4 acc[8];
  #pragma unroll
  for (int i = 0; i < 8; ++i) acc[i] = (fx4){0.f, 0.f, 0.f, 0.f};

  const unsigned short* arow = Ob + (size_t)(m0 + tn) * 512;
  for (int k0 = 0; k0 < 512; k0 += 32) {
    bfx8 af = ldbf8(arow + k0 + quad * 8);
    #pragma unroll
    for (int nt = 0; nt < 8; ++nt) {
      const unsigned short* wp = Wfcb + (size_t)(wave * 128 + nt * 16 + tn) * 512 + k0 + quad * 8;
      acc[nt] = MFMA16(af, ldbf8(wp), acc[nt]);
    }
  }
  #pragma unroll
  for (int nt = 0; nt < 8; ++nt) {
    int col = wave * 128 + nt * 16 + tn;
    #pragma unroll
    for (int i = 0; i < 4; ++i) xb[(quad * 4 + i) * XPITCH + col] = acc[nt][i];
  }
  __syncthreads();

  #pragma unroll
  for (int ri = 0; ri < 4; ++ri) {
    int r = wave * 4 + ri;
    int row = m0 + r;
    float* xr = xb + r * XPITCH;
    const float* qr = resid + (size_t)row * 512;
    float sum = 0.f, sq = 0.f;
    #pragma unroll
    for (int it = 0; it < 2; ++it) {
      int i4 = lane + it * 64;  // 0..127
      fx4 x = *reinterpret_cast<fx4*>(xr + i4 * 4);
      fx4 bb = *reinterpret_cast<const fx4*>(bfc + i4 * 4);
      fx4 rr = *reinterpret_cast<const fx4*>(qr + i4 * 4);
      x = x + bb + rr;
      *reinterpret_cast<fx4*>(xr + i4 * 4) = x;
      sum += x[0] + x[1] + x[2] + x[3];
      sq  += x[0]*x[0] + x[1]*x[1] + x[2]*x[2] + x[3]*x[3];
    }
    #pragma unroll
    for (int off = 32; off; off >>= 1) {
      sum += __shfl_xor(sum, off);
      sq  += __shfl_xor(sq, off);
    }
    float mu = sum * (1.f / 512.f);
    float var = sq * (1.f / 512.f) - mu * mu;
    float rstd = rsqrtf(var + 1e-5f);
    #pragma unroll
    for (int it = 0; it < 2; ++it) {
      int i4 = lane + it * 64;
      fx4 x = *reinterpret_cast<fx4*>(xr + i4 * 4);
      fx4 gg = *reinterpret_cast<const fx4*>(lng + i4 * 4);
      fx4 be = *reinterpret_cast<const fx4*>(lnb + i4 * 4);
      fx4 y = (x - mu) * rstd * gg + be;
      *reinterpret_cast<fx4*>(out + (size_t)row * 512 + i4 * 4) = y;
    }
  }
}

// ---------------- launcher ------------------------------------------------------
extern "C" void kernel_launch(void* const* d_in, const int* in_sizes, int n_in,
                              void* d_out, int out_size, void* d_ws, size_t ws_size,
                              hipStream_t stream) {
  const float* q    = (const float*)d_in[0];
  const float* k    = (const float*)d_in[1];
  const float* v    = (const float*)d_in[2];
  const int*   mask = (const int*)d_in[3];
  const float* gate = (const float*)d_in[4];
  const float* w_qs = (const float*)d_in[5];
  const float* b_qs = (const float*)d_in[6];
  const float* w_ks = (const float*)d_in[7];
  const float* b_ks = (const float*)d_in[8];
  const float* w_vs = (const float*)d_in[9];
  const float* b_vs = (const float*)d_in[10];
  const float* w_fc = (const float*)d_in[11];
  const float* b_fc = (const float*)d_in[12];
  const float* ln_g = (const float*)d_in[13];
  const float* ln_b = (const float*)d_in[14];
  float* out = (float*)d_out;

  char* ws = (char*)d_ws;
  unsigned short* Qb = (unsigned short*)(ws);                    //  4 MB
  unsigned short* Kb = (unsigned short*)(ws + 4194304);          //  4 MB
  unsigned short* Vt = (unsigned short*)(ws + 8388608);          //  4 MB
  unsigned short* Ob = (unsigned short*)(ws + 12582912);         //  4 MB
  unsigned short* Wb = (unsigned short*)(ws + 16777216);         //  2 MB (4 x 512KB)
  unsigned long long* mbits = (unsigned long long*)(ws + 18874368);  // 1 MB

  float* attn = out + 2097152;   // [B,H,L,L] f32 attention output region

  k_prep<<<33792, 256, 0, stream>>>(w_qs, w_ks, w_vs, w_fc, Wb, mask, mbits);
  k_proj<<<dim3(64, 8, 3), 256, 0, stream>>>(q, k, v, Wb, b_qs, b_ks, b_vs, Qb, Kb, Vt);
  k_attn<<<4096, 256, 0, stream>>>(Qb, Kb, Vt, gate, mbits, attn, Ob);
  k_fc_ln<<<256, 256, 0, stream>>>(Ob, Wb + 786432, b_fc, q, ln_g, ln_b, out);
}

// Round 4
// 699.454 us; speedup vs baseline: 1.3151x; 1.1639x over previous
//
#include <hip/hip_runtime.h>
#include <stdint.h>

// Problem constants
// B=2, L=2048, D=512, H=8, DK=DV=64, TEMP=8, LN_EPS=1e-5

typedef float fx4 __attribute__((ext_vector_type(4)));
typedef short bfx8 __attribute__((ext_vector_type(8)));
typedef short sx4 __attribute__((ext_vector_type(4)));

#define MFMA16(a, b, c) __builtin_amdgcn_mfma_f32_16x16x32_bf16((a), (b), (c), 0, 0, 0)

__device__ __forceinline__ unsigned short f2bf(float f) {
  union { float f; uint32_t u; } v; v.f = f;
  uint32_t r = v.u + 0x7FFFu + ((v.u >> 16) & 1u);  // RNE
  return (unsigned short)(r >> 16);
}

__device__ __forceinline__ bfx8 ldbf8(const unsigned short* p) {
  return *reinterpret_cast<const bfx8*>(p);
}

__device__ __forceinline__ bfx8 cvt8(const float* p) {
  fx4 a = *reinterpret_cast<const fx4*>(p);
  fx4 b = *reinterpret_cast<const fx4*>(p + 4);
  bfx8 r;
  r[0] = (short)f2bf(a[0]); r[1] = (short)f2bf(a[1]);
  r[2] = (short)f2bf(a[2]); r[3] = (short)f2bf(a[3]);
  r[4] = (short)f2bf(b[0]); r[5] = (short)f2bf(b[1]);
  r[6] = (short)f2bf(b[2]); r[7] = (short)f2bf(b[3]);
  return r;
}

// ---------------- kernel 0: weight bf16 convert + mask bitpack (fused) ----------
__global__ __launch_bounds__(256) void k_prep(const float* __restrict__ s0,
                                              const float* __restrict__ s1,
                                              const float* __restrict__ s2,
                                              const float* __restrict__ s3,
                                              unsigned short* __restrict__ dst,
                                              const int* __restrict__ mask,
                                              unsigned long long* __restrict__ mbits) {
  int bid = blockIdx.x;
  if (bid < 1024) {
    int y = bid >> 8;
    const float* s = (y == 0) ? s0 : (y == 1) ? s1 : (y == 2) ? s2 : s3;
    int i = ((bid & 255) * 256 + threadIdx.x) * 4;
    fx4 v = *reinterpret_cast<const fx4*>(s + i);
    sx4 o;
    o[0] = (short)f2bf(v[0]); o[1] = (short)f2bf(v[1]);
    o[2] = (short)f2bf(v[2]); o[3] = (short)f2bf(v[3]);
    *reinterpret_cast<sx4*>(dst + y * 262144 + i) = o;
  } else {
    int i = (bid - 1024) * 256 + threadIdx.x;  // total 8388608
    unsigned long long b = __ballot(mask[i] != 0);
    if ((threadIdx.x & 63) == 0) mbits[i >> 6] = b;
  }
}

// ---------------- kernel 1: projection GEMMs, all 3 in one launch (blockIdx.z) --
// z=0: Qb [B,H,L,64] ; z=1: Kb same ; z=2: Vt [B,H,64,L] (transposed)
__global__ __launch_bounds__(256) void k_proj(const float* __restrict__ Xq,
                                              const float* __restrict__ Xk,
                                              const float* __restrict__ Xv,
                                              const unsigned short* __restrict__ Wb,
                                              const float* __restrict__ bq,
                                              const float* __restrict__ bk,
                                              const float* __restrict__ bv,
                                              unsigned short* __restrict__ Qb,
                                              unsigned short* __restrict__ Kb,
                                              unsigned short* __restrict__ Vt) {
  int z = blockIdx.z;
  const float* X = (z == 0) ? Xq : (z == 1) ? Xk : Xv;
  const unsigned short* W = Wb + (size_t)z * 262144;
  const float* bias = (z == 0) ? bq : (z == 1) ? bk : bv;
  unsigned short* dst = (z == 0) ? Qb : (z == 1) ? Kb : Vt;

  int wave = threadIdx.x >> 6, lane = threadIdx.x & 63;
  int quad = lane >> 4, tn = lane & 15;
  int m0 = blockIdx.x * 64 + wave * 16;   // 64 blocks.x -> 4096 rows
  int n0 = blockIdx.y * 64;               // 8 blocks.y  -> 512 cols
  fx4 acc[4];
  #pragma unroll
  for (int i = 0; i < 4; ++i) acc[i] = (fx4){0.f, 0.f, 0.f, 0.f};

  const float* xrow = X + (size_t)(m0 + tn) * 512;
  for (int k0 = 0; k0 < 512; k0 += 32) {
    bfx8 af = cvt8(xrow + k0 + quad * 8);
    #pragma unroll
    for (int nt = 0; nt < 4; ++nt) {
      const unsigned short* wp = W + (size_t)(n0 + nt * 16 + tn) * 512 + k0 + quad * 8;
      acc[nt] = MFMA16(af, ldbf8(wp), acc[nt]);
    }
  }

  #pragma unroll
  for (int nt = 0; nt < 4; ++nt) {
    int n = n0 + nt * 16 + tn;
    int h = n >> 6, dd = n & 63;
    float bvv = bias[n];
    if (z == 2) {
      int r0 = m0 + quad * 4;          // 4 consecutive rows, same batch
      int b = r0 >> 11, l = r0 & 2047;
      sx4 o;
      #pragma unroll
      for (int i = 0; i < 4; ++i) o[i] = (short)f2bf(acc[nt][i] + bvv);
      unsigned short* vp = dst + (size_t)((b * 8 + h) * 64 + dd) * 2048 + l;
      *reinterpret_cast<sx4*>(vp) = o;
    } else {
      #pragma unroll
      for (int i = 0; i < 4; ++i) {
        int r = m0 + quad * 4 + i;
        int b = r >> 11, l = r & 2047;
        dst[(size_t)((b * 8 + h) * 2048 + l) * 64 + dd] = f2bf(acc[nt][i] + bvv);
      }
    }
  }
}

// ---------------- kernel 2: single-pass attention, 16 q-rows, 8 waves ----------
// Phase A: QK^T -> LDS raw S; ONE gate fx4 prefetched per iteration so the HBM
//          gate stream flows under the MFMA phase (regs gv[16], fully unrolled).
// Phase B: per wave 2 rows: LDS row -> regs, gate*mask, softmax, write normalized
//          attn f32 (coalesced) + normalized bf16 P into the row's LDS front.
// Phase D: waves 0..3: O = P @ V via pure ldbf8+MFMA (no cvt8 on critical path).
#define SPITCH 2052
__global__ __launch_bounds__(512) void k_attn(const unsigned short* __restrict__ Qb,
                                              const unsigned short* __restrict__ Kb,
                                              const unsigned short* __restrict__ Vt,
                                              const float* __restrict__ gate,
                                              const unsigned long long* __restrict__ mbits,
                                              float* __restrict__ attn_out,
                                              unsigned short* __restrict__ Ob) {
  __shared__ float S[16 * SPITCH];   // 131.3 KB score strip (front reused for bf16 P)

  int wave = threadIdx.x >> 6, lane = threadIdx.x & 63;
  int quad = lane >> 4, tn = lane & 15;

  int lin = blockIdx.x;            // 0..2047
  int xcd = lin & 7;
  int ix  = lin >> 3;              // 0..255
  int bh  = xcd * 2 + (ix >> 7);   // each XCD owns 2 (b,h): K/V stay L2-resident
  int qt  = ix & 127;
  int b = bh >> 3, h = bh & 7;
  int q0 = qt * 16;

  // ---- phase A: raw scores (QK^T)/8 -> LDS, gate prefetch interleaved --------
  const unsigned short* Qbase = Qb + ((size_t)bh * 2048 + q0) * 64;
  bfx8 aq0 = ldbf8(Qbase + tn * 64 + quad * 8);
  bfx8 aq1 = ldbf8(Qbase + tn * 64 + 32 + quad * 8);
  const unsigned short* Kbase = Kb + (size_t)bh * 2048 * 64;
  const float* grow0 = gate + ((size_t)bh * 2048 + q0 + wave * 2) * 2048;

  fx4 gv[16];   // 2 rows x 8 fx4 chunks, fully unrolled -> stays in VGPRs
  #pragma unroll
  for (int i2 = 0; i2 < 16; ++i2) {
    int kt = wave + i2 * 8;        // 16 key-tiles per wave, 8 waves cover 128
    int key0 = kt * 16;
    gv[i2] = *reinterpret_cast<const fx4*>(
        grow0 + (size_t)(i2 >> 3) * 2048 + (size_t)(lane + (i2 & 7) * 64) * 4);
    const unsigned short* kp = Kbase + (size_t)(key0 + tn) * 64 + quad * 8;
    bfx8 b0 = ldbf8(kp);
    bfx8 b1 = ldbf8(kp + 32);
    fx4 d = (fx4){0.f, 0.f, 0.f, 0.f};
    d = MFMA16(aq0, b0, d);
    d = MFMA16(aq1, b1, d);
    #pragma unroll
    for (int i = 0; i < 4; ++i)
      S[(quad * 4 + i) * SPITCH + key0 + tn] = d[i] * 0.125f;
  }
  __syncthreads();

  // ---- phase B: wave w owns rows 2w, 2w+1 ------------------------------------
  #pragma unroll
  for (int rr = 0; rr < 2; ++rr) {
    int r = wave * 2 + rr;
    float* srow = S + r * SPITCH;
    const unsigned long long* mrow = mbits + (size_t)(b * 2048 + q0 + r) * 32;
    unsigned long long mv[8];
    #pragma unroll
    for (int it = 0; it < 8; ++it) mv[it] = mrow[(lane + it * 64) >> 4];
    fx4 sv[8];
    float lmax = -3.0e38f;
    #pragma unroll
    for (int it = 0; it < 8; ++it) {
      int k4 = lane + it * 64;     // fx4 index 0..511
      fx4 s = *reinterpret_cast<fx4*>(srow + k4 * 4);
      fx4 g = gv[rr * 8 + it];
      int sh = (k4 & 15) * 4;
      #pragma unroll
      for (int i = 0; i < 4; ++i) {
        float vv = s[i] * g[i];
        if ((mv[it] >> (sh + i)) & 1ull) vv = -3.0e38f;
        s[i] = vv;
        lmax = fmaxf(lmax, vv);
      }
      sv[it] = s;
    }
    #pragma unroll
    for (int off = 32; off; off >>= 1) lmax = fmaxf(lmax, __shfl_xor(lmax, off));
    float lsum = 0.f;
    #pragma unroll
    for (int it = 0; it < 8; ++it) {
      fx4 s = sv[it];
      #pragma unroll
      for (int i = 0; i < 4; ++i) {
        float p = __expf(s[i] - lmax);
        s[i] = p;
        lsum += p;
      }
      sv[it] = s;
    }
    #pragma unroll
    for (int off = 32; off; off >>= 1) lsum += __shfl_xor(lsum, off);
    float inv = 1.0f / lsum;
    float* orow = attn_out + ((size_t)bh * 2048 + q0 + r) * 2048;
    unsigned short* pb = reinterpret_cast<unsigned short*>(srow);  // row front, bf16 P
    #pragma unroll
    for (int it = 0; it < 8; ++it) {
      int k4 = lane + it * 64;
      fx4 p = sv[it] * inv;
      *reinterpret_cast<fx4*>(orow + k4 * 4) = p;   // normalized attn (coalesced)
      sx4 pk;
      #pragma unroll
      for (int i = 0; i < 4; ++i) pk[i] = (short)f2bf(p[i]);
      *reinterpret_cast<sx4*>(pb + k4 * 4) = pk;    // normalized bf16 P for PV
    }
  }
  __syncthreads();

  // ---- phase D: waves 0..3: O = P @ V, wave w covers dv [16w,16w+16) ---------
  if (wave < 4) {
    fx4 acc = (fx4){0.f, 0.f, 0.f, 0.f};
    const unsigned short* vbase = Vt + ((size_t)bh * 64 + wave * 16 + tn) * 2048;
    const unsigned short* prow = reinterpret_cast<const unsigned short*>(S + tn * SPITCH);
    #pragma unroll 8
    for (int kt = 0; kt < 64; ++kt) {
      bfx8 af = ldbf8(prow + kt * 32 + quad * 8);
      bfx8 bv = ldbf8(vbase + kt * 32 + quad * 8);
      acc = MFMA16(af, bv, acc);
    }
    #pragma unroll
    for (int i = 0; i < 4; ++i) {
      int qg = q0 + quad * 4 + i;
      Ob[(size_t)(b * 2048 + qg) * 512 + h * 64 + wave * 16 + tn] = f2bf(acc[i]);
    }
  }
}

// ---------------- kernel 3: FC + bias + residual + LayerNorm --------------------
#define XPITCH 516
__global__ __launch_bounds__(256) void k_fc_ln(const unsigned short* __restrict__ Ob,
                                               const unsigned short* __restrict__ Wfcb,
                                               const float* __restrict__ bfc,
                                               const float* __restrict__ resid,
                                               const float* __restrict__ lng,
                                               const float* __restrict__ lnb,
                                               float* __restrict__ out) {
  __shared__ float xb[16 * XPITCH];
  int wave = threadIdx.x >> 6, lane = threadIdx.x & 63;
  int quad = lane >> 4, tn = lane & 15;
  int m0 = blockIdx.x * 16;   // 256 blocks -> 4096 rows

  fx4 acc[8];
  #pragma unroll
  for (int i = 0; i < 8; ++i) acc[i] = (fx4){0.f, 0.f, 0.f, 0.f};

  const unsigned short* arow = Ob + (size_t)(m0 + tn) * 512;
  for (int k0 = 0; k0 < 512; k0 += 32) {
    bfx8 af = ldbf8(arow + k0 + quad * 8);
    #pragma unroll
    for (int nt = 0; nt < 8; ++nt) {
      const unsigned short* wp = Wfcb + (size_t)(wave * 128 + nt * 16 + tn) * 512 + k0 + quad * 8;
      acc[nt] = MFMA16(af, ldbf8(wp), acc[nt]);
    }
  }
  #pragma unroll
  for (int nt = 0; nt < 8; ++nt) {
    int col = wave * 128 + nt * 16 + tn;
    #pragma unroll
    for (int i = 0; i < 4; ++i) xb[(quad * 4 + i) * XPITCH + col] = acc[nt][i];
  }
  __syncthreads();

  #pragma unroll
  for (int ri = 0; ri < 4; ++ri) {
    int r = wave * 4 + ri;
    int row = m0 + r;
    float* xr = xb + r * XPITCH;
    const float* qr = resid + (size_t)row * 512;
    float sum = 0.f, sq = 0.f;
    #pragma unroll
    for (int it = 0; it < 2; ++it) {
      int i4 = lane + it * 64;  // 0..127
      fx4 x = *reinterpret_cast<fx4*>(xr + i4 * 4);
      fx4 bb = *reinterpret_cast<const fx4*>(bfc + i4 * 4);
      fx4 rr = *reinterpret_cast<const fx4*>(qr + i4 * 4);
      x = x + bb + rr;
      *reinterpret_cast<fx4*>(xr + i4 * 4) = x;
      sum += x[0] + x[1] + x[2] + x[3];
      sq  += x[0]*x[0] + x[1]*x[1] + x[2]*x[2] + x[3]*x[3];
    }
    #pragma unroll
    for (int off = 32; off; off >>= 1) {
      sum += __shfl_xor(sum, off);
      sq  += __shfl_xor(sq, off);
    }
    float mu = sum * (1.f / 512.f);
    float var = sq * (1.f / 512.f) - mu * mu;
    float rstd = rsqrtf(var + 1e-5f);
    #pragma unroll
    for (int it = 0; it < 2; ++it) {
      int i4 = lane + it * 64;
      fx4 x = *reinterpret_cast<fx4*>(xr + i4 * 4);
      fx4 gg = *reinterpret_cast<const fx4*>(lng + i4 * 4);
      fx4 be = *reinterpret_cast<const fx4*>(lnb + i4 * 4);
      fx4 y = (x - mu) * rstd * gg + be;
      *reinterpret_cast<fx4*>(out + (size_t)row * 512 + i4 * 4) = y;
    }
  }
}

// ---------------- launcher ------------------------------------------------------
extern "C" void kernel_launch(void* const* d_in, const int* in_sizes, int n_in,
                              void* d_out, int out_size, void* d_ws, size_t ws_size,
                              hipStream_t stream) {
  const float* q    = (const float*)d_in[0];
  const float* k    = (const float*)d_in[1];
  const float* v    = (const float*)d_in[2];
  const int*   mask = (const int*)d_in[3];
  const float* gate = (const float*)d_in[4];
  const float* w_qs = (const float*)d_in[5];
  const float* b_qs = (const float*)d_in[6];
  const float* w_ks = (const float*)d_in[7];
  const float* b_ks = (const float*)d_in[8];
  const float* w_vs = (const float*)d_in[9];
  const float* b_vs = (const float*)d_in[10];
  const float* w_fc = (const float*)d_in[11];
  const float* b_fc = (const float*)d_in[12];
  const float* ln_g = (const float*)d_in[13];
  const float* ln_b = (const float*)d_in[14];
  float* out = (float*)d_out;

  char* ws = (char*)d_ws;
  unsigned short* Qb = (unsigned short*)(ws);                    //  4 MB
  unsigned short* Kb = (unsigned short*)(ws + 4194304);          //  4 MB
  unsigned short* Vt = (unsigned short*)(ws + 8388608);          //  4 MB
  unsigned short* Ob = (unsigned short*)(ws + 12582912);         //  4 MB
  unsigned short* Wb = (unsigned short*)(ws + 16777216);         //  2 MB (4 x 512KB)
  unsigned long long* mbits = (unsigned long long*)(ws + 18874368);  // 1 MB

  float* attn = out + 2097152;   // [B,H,L,L] f32 attention output region

  k_prep<<<33792, 256, 0, stream>>>(w_qs, w_ks, w_vs, w_fc, Wb, mask, mbits);
  k_proj<<<dim3(64, 8, 3), 256, 0, stream>>>(q, k, v, Wb, b_qs, b_ks, b_vs, Qb, Kb, Vt);
  k_attn<<<2048, 512, 0, stream>>>(Qb, Kb, Vt, gate, mbits, attn, Ob);
  k_fc_ln<<<256, 256, 0, stream>>>(Ob, Wb + 786432, b_fc, q, ln_g, ln_b, out);
}